// Round 1
// baseline (90.796 us; speedup 1.0000x reference)
//
#include <hip/hip_runtime.h>
#include <float.h>

#define Bsz 2048
#define Nn  1024
#define Dd  256

// ---------------------------------------------------------------------------
// scalar params computed on-device from int inputs (graph-capture safe)
// ---------------------------------------------------------------------------
__device__ __forceinline__ void som_params(const int* __restrict__ step,
                                           const int* __restrict__ total,
                                           float* taxa, float* inv2s2) {
    float frac = (float)(*step) / (float)(*total);
    float e = __expf(-frac);
    *taxa = 0.5f * e;
    float sigma = 16.0f * e;          // SIGMA_INICIAL = max(32,32)/2
    *inv2s2 = 1.0f / (2.0f * sigma * sigma);
}

// ---------------------------------------------------------------------------
// kernel 1: w2[n] = sum_d W[n,d]^2        (one wave per row)
// ---------------------------------------------------------------------------
__global__ __launch_bounds__(256) void w2_kernel(const float* __restrict__ W,
                                                 float* __restrict__ w2) {
    int gw   = (blockIdx.x * 256 + threadIdx.x) >> 6;   // global wave id == row
    int lane = threadIdx.x & 63;
    float4 v = ((const float4*)(W + gw * Dd))[lane];    // 64 lanes * 4 = 256
    float s = v.x*v.x + v.y*v.y + v.z*v.z + v.w*v.w;
    #pragma unroll
    for (int m = 32; m; m >>= 1) s += __shfl_xor(s, m, 64);
    if (lane == 0) w2[gw] = s;
}

// ---------------------------------------------------------------------------
// kernel 2: partial argmin of score[b,n] = w2[n] - 2*dot(X[b],W[n])
// grid (32 bgroups of 64, 16 ngroups of 64); block 256; micro-tile 4b x 4n
// ---------------------------------------------------------------------------
__global__ __launch_bounds__(256) void bmu_partial(
    const float* __restrict__ X, const float* __restrict__ W,
    const float* __restrict__ w2, float* __restrict__ pval,
    int* __restrict__ pidx)
{
    __shared__ float Xs[64][68];   // +4 pad: row stride 272B, 16B aligned
    __shared__ float Ws[64][68];
    __shared__ float w2s[64];

    const int t  = threadIdx.x;
    const int b0 = blockIdx.x * 64;
    const int n0 = blockIdx.y * 64;

    if (t < 64) w2s[t] = w2[n0 + t];

    const int bp = t >> 4;   // 0..15 -> b rows bp*4+i
    const int np = t & 15;   // 0..15 -> n cols j*16+np

    float acc[4][4];
    #pragma unroll
    for (int i = 0; i < 4; ++i)
        #pragma unroll
        for (int j = 0; j < 4; ++j) acc[i][j] = 0.f;

    for (int kc = 0; kc < 4; ++kc) {        // K = 256 in chunks of 64
        __syncthreads();
        #pragma unroll
        for (int s = 0; s < 4; ++s) {       // stage 64x64 of X and W
            int flat = s * 1024 + t * 4;
            int row = flat >> 6, col = flat & 63;
            *(float4*)&Xs[row][col] = *(const float4*)&X[(b0 + row) * Dd + kc * 64 + col];
            *(float4*)&Ws[row][col] = *(const float4*)&W[(n0 + row) * Dd + kc * 64 + col];
        }
        __syncthreads();
        #pragma unroll
        for (int k = 0; k < 64; k += 4) {
            float4 xv[4], wv[4];
            #pragma unroll
            for (int i = 0; i < 4; ++i) xv[i] = *(const float4*)&Xs[bp * 4 + i][k];
            #pragma unroll
            for (int j = 0; j < 4; ++j) wv[j] = *(const float4*)&Ws[j * 16 + np][k];
            #pragma unroll
            for (int i = 0; i < 4; ++i)
                #pragma unroll
                for (int j = 0; j < 4; ++j) {
                    acc[i][j] = fmaf(xv[i].x, wv[j].x, acc[i][j]);
                    acc[i][j] = fmaf(xv[i].y, wv[j].y, acc[i][j]);
                    acc[i][j] = fmaf(xv[i].z, wv[j].z, acc[i][j]);
                    acc[i][j] = fmaf(xv[i].w, wv[j].w, acc[i][j]);
                }
        }
    }

    // per-thread argmin over its 4 n's, per b row
    float mv[4]; int mi[4];
    #pragma unroll
    for (int i = 0; i < 4; ++i) { mv[i] = FLT_MAX; mi[i] = 0x7fffffff; }
    #pragma unroll
    for (int j = 0; j < 4; ++j) {
        int nl = j * 16 + np;
        float wsq = w2s[nl];
        int n = n0 + nl;
        #pragma unroll
        for (int i = 0; i < 4; ++i) {
            float sc = wsq - 2.f * acc[i][j];
            if (sc < mv[i] || (sc == mv[i] && n < mi[i])) { mv[i] = sc; mi[i] = n; }
        }
    }
    // reduce across the 16 np lanes (within-wave, 16-aligned groups)
    #pragma unroll
    for (int m = 1; m < 16; m <<= 1) {
        #pragma unroll
        for (int i = 0; i < 4; ++i) {
            float ov = __shfl_xor(mv[i], m, 64);
            int   oi = __shfl_xor(mi[i], m, 64);
            if (ov < mv[i] || (ov == mv[i] && oi < mi[i])) { mv[i] = ov; mi[i] = oi; }
        }
    }
    if (np == 0) {
        #pragma unroll
        for (int i = 0; i < 4; ++i) {
            int b = b0 + bp * 4 + i;
            pval[b * 16 + blockIdx.y] = mv[i];
            pidx[b * 16 + blockIdx.y] = mi[i];
        }
    }
}

// ---------------------------------------------------------------------------
// kernel 2b: final argmin over 16 partials; store BMU grid location
// ---------------------------------------------------------------------------
__global__ __launch_bounds__(256) void bmu_reduce(
    const float* __restrict__ pval, const int* __restrict__ pidx,
    const float* __restrict__ loc, float2* __restrict__ bloc)
{
    int b = blockIdx.x * 256 + threadIdx.x;
    float mv = FLT_MAX; int mi = 0x7fffffff;
    #pragma unroll
    for (int g = 0; g < 16; ++g) {
        float v = pval[b * 16 + g]; int id = pidx[b * 16 + g];
        if (v < mv || (v == mv && id < mi)) { mv = v; mi = id; }
    }
    bloc[b] = make_float2(loc[2 * mi], loc[2 * mi + 1]);
}

// ---------------------------------------------------------------------------
// kernel 3: acc[n,d] += sum_b h[b,n]*X[b,d]; hsum[n] += sum_b h[b,n]
// grid (16 n-tiles, 4 d-tiles, 8 k-chunks of 256 b); block 256; micro 4n x 4d
// ---------------------------------------------------------------------------
__global__ __launch_bounds__(256) void acc_kernel(
    const float* __restrict__ X, const float* __restrict__ loc,
    const float2* __restrict__ bloc, const int* __restrict__ step,
    const int* __restrict__ total, float* __restrict__ acc,
    float* __restrict__ hsum)
{
    __shared__ float Hs[64][64];
    __shared__ float Xs[64][64];

    const int t  = threadIdx.x;
    const int n0 = blockIdx.x * 64;
    const int d0 = blockIdx.y * 64;
    const int kg = blockIdx.z;

    float taxa, inv2s2;
    som_params(step, total, &taxa, &inv2s2);

    const int np = t >> 4, dp = t & 15;
    float a[4][4];
    #pragma unroll
    for (int i = 0; i < 4; ++i)
        #pragma unroll
        for (int j = 0; j < 4; ++j) a[i][j] = 0.f;
    float hs[4] = {0.f, 0.f, 0.f, 0.f};

    for (int sub = 0; sub < 4; ++sub) {     // 256 b per chunk, sub-blocks of 64
        const int b0 = kg * 256 + sub * 64;
        __syncthreads();
        #pragma unroll
        for (int s = 0; s < 16; ++s) {      // compute 64x64 h tile
            int idx = s * 256 + t;
            int bb = idx >> 6, nn = idx & 63;
            float2 bl = bloc[b0 + bb];
            int n = n0 + nn;
            float dx = loc[2 * n]     - bl.x;
            float dy = loc[2 * n + 1] - bl.y;
            Hs[bb][nn] = __expf(-(dx * dx + dy * dy) * inv2s2);
        }
        #pragma unroll
        for (int s = 0; s < 4; ++s) {       // stage 64x64 of X
            int flat = s * 1024 + t * 4;
            int row = flat >> 6, col = flat & 63;
            *(float4*)&Xs[row][col] = *(const float4*)&X[(b0 + row) * Dd + d0 + col];
        }
        __syncthreads();
        #pragma unroll 8
        for (int bb = 0; bb < 64; ++bb) {
            float4 h4 = *(const float4*)&Hs[bb][np * 4];
            float4 x4 = *(const float4*)&Xs[bb][dp * 4];
            hs[0] += h4.x; hs[1] += h4.y; hs[2] += h4.z; hs[3] += h4.w;
            a[0][0] = fmaf(h4.x, x4.x, a[0][0]); a[0][1] = fmaf(h4.x, x4.y, a[0][1]);
            a[0][2] = fmaf(h4.x, x4.z, a[0][2]); a[0][3] = fmaf(h4.x, x4.w, a[0][3]);
            a[1][0] = fmaf(h4.y, x4.x, a[1][0]); a[1][1] = fmaf(h4.y, x4.y, a[1][1]);
            a[1][2] = fmaf(h4.y, x4.z, a[1][2]); a[1][3] = fmaf(h4.y, x4.w, a[1][3]);
            a[2][0] = fmaf(h4.z, x4.x, a[2][0]); a[2][1] = fmaf(h4.z, x4.y, a[2][1]);
            a[2][2] = fmaf(h4.z, x4.z, a[2][2]); a[2][3] = fmaf(h4.z, x4.w, a[2][3]);
            a[3][0] = fmaf(h4.w, x4.x, a[3][0]); a[3][1] = fmaf(h4.w, x4.y, a[3][1]);
            a[3][2] = fmaf(h4.w, x4.z, a[3][2]); a[3][3] = fmaf(h4.w, x4.w, a[3][3]);
        }
    }
    #pragma unroll
    for (int i = 0; i < 4; ++i) {
        int n = n0 + np * 4 + i;
        #pragma unroll
        for (int j = 0; j < 4; ++j)
            atomicAdd(&acc[n * Dd + d0 + dp * 4 + j], a[i][j]);
    }
    if (blockIdx.y == 0 && dp == 0) {
        #pragma unroll
        for (int i = 0; i < 4; ++i) atomicAdd(&hsum[n0 + np * 4 + i], hs[i]);
    }
}

// ---------------------------------------------------------------------------
// kernel 4: out = W + taxa*(acc - hsum*W)/B
// ---------------------------------------------------------------------------
__global__ __launch_bounds__(256) void finish_kernel(
    const float* __restrict__ W, const float* __restrict__ acc,
    const float* __restrict__ hsum, const int* __restrict__ step,
    const int* __restrict__ total, float* __restrict__ out)
{
    float taxa, inv2s2;
    som_params(step, total, &taxa, &inv2s2);
    const float invB = 1.0f / 2048.0f;
    int i = blockIdx.x * 256 + threadIdx.x;   // float4 index, 65536 total
    int n = i >> 6;                            // 64 float4 per row
    float hsn = hsum[n];
    float4 w = ((const float4*)W)[i];
    float4 a = ((const float4*)acc)[i];
    float4 o;
    o.x = w.x + taxa * (a.x - hsn * w.x) * invB;
    o.y = w.y + taxa * (a.y - hsn * w.y) * invB;
    o.z = w.z + taxa * (a.z - hsn * w.z) * invB;
    o.w = w.w + taxa * (a.w - hsn * w.w) * invB;
    ((float4*)out)[i] = o;
}

// ---------------------------------------------------------------------------
extern "C" void kernel_launch(void* const* d_in, const int* in_sizes, int n_in,
                              void* d_out, int out_size, void* d_ws, size_t ws_size,
                              hipStream_t stream)
{
    const float* X    = (const float*)d_in[0];
    const float* W    = (const float*)d_in[1];
    const float* loc  = (const float*)d_in[2];
    const int* step   = (const int*)d_in[3];
    const int* total  = (const int*)d_in[4];
    float* out = (float*)d_out;

    // ws layout (floats): acc[262144] | hsum[1024] | w2[1024] | pval[32768]
    //                     | pidx[32768] | bloc(float2)[2048]   (~1.28 MB)
    float*  acc  = (float*)d_ws;
    float*  hsum = acc + 262144;
    float*  w2   = hsum + 1024;
    float*  pval = w2 + 1024;
    int*    pidx = (int*)(pval + 32768);
    float2* bloc = (float2*)(pidx + 32768);

    hipMemsetAsync(d_ws, 0, (262144 + 1024) * sizeof(float), stream);

    w2_kernel   <<<256, 256, 0, stream>>>(W, w2);
    bmu_partial <<<dim3(32, 16), 256, 0, stream>>>(X, W, w2, pval, pidx);
    bmu_reduce  <<<8, 256, 0, stream>>>(pval, pidx, loc, bloc);
    acc_kernel  <<<dim3(16, 4, 8), 256, 0, stream>>>(X, loc, bloc, step, total, acc, hsum);
    finish_kernel<<<256, 256, 0, stream>>>(W, acc, hsum, step, total, out);
}

// Round 2
// 59.568 us; speedup vs baseline: 1.5243x; 1.5243x over previous
//
#include <hip/hip_runtime.h>
#include <float.h>

#define Bsz 2048
#define Nn  1024
#define Dd  256

typedef __attribute__((ext_vector_type(8))) short bf16x8;
typedef __attribute__((ext_vector_type(4))) float f32x4;

// round-to-nearest-even f32 -> bf16 bits
__device__ __forceinline__ unsigned short bfr(float x) {
    unsigned u = __float_as_uint(x);
    u += 0x7fffu + ((u >> 16) & 1u);
    return (unsigned short)(u >> 16);
}
__device__ __forceinline__ float bf2f(unsigned short h) {
    return __uint_as_float(((unsigned)h) << 16);
}

__device__ __forceinline__ void som_params(const int* __restrict__ step,
                                           const int* __restrict__ total,
                                           float* taxa, float* inv2s2) {
    float frac = (float)(*step) / (float)(*total);
    float e = __expf(-frac);
    *taxa = 0.5f * e;
    float sigma = 16.0f * e;              // SIGMA_INICIAL = 16
    *inv2s2 = 1.0f / (2.0f * sigma * sigma);
}

// ---------------------------------------------------------------------------
// prep: hi/lo bf16 split of a row-major [rows][256] f32 matrix (+optional w2)
// one wave per row; 4 rows per 256-thread block
// ---------------------------------------------------------------------------
__global__ __launch_bounds__(256) void prep_split(
    const float* __restrict__ src, ushort* __restrict__ hi,
    ushort* __restrict__ lo, float* __restrict__ w2)
{
    int row  = blockIdx.x * 4 + (threadIdx.x >> 6);
    int lane = threadIdx.x & 63;
    float4 v = ((const float4*)(src + (size_t)row * Dd))[lane];
    if (w2) {
        float s = v.x*v.x + v.y*v.y + v.z*v.z + v.w*v.w;
        #pragma unroll
        for (int m = 32; m; m >>= 1) s += __shfl_xor(s, m, 64);
        if (lane == 0) w2[row] = s;
    }
    ushort4 h, l;
    h.x = bfr(v.x); l.x = bfr(v.x - bf2f(h.x));
    h.y = bfr(v.y); l.y = bfr(v.y - bf2f(h.y));
    h.z = bfr(v.z); l.z = bfr(v.z - bf2f(h.z));
    h.w = bfr(v.w); l.w = bfr(v.w - bf2f(h.w));
    *(ushort4*)&hi[(size_t)row * Dd + lane * 4] = h;
    *(ushort4*)&lo[(size_t)row * Dd + lane * 4] = l;
}

// ---------------------------------------------------------------------------
// prep: Xt[d][b] = bf16(X[b][d])   (transpose via LDS tile)
// grid (32 b-tiles, 4 d-tiles), block 256
// ---------------------------------------------------------------------------
__global__ __launch_bounds__(256) void prep_xt(const float* __restrict__ X,
                                               ushort* __restrict__ Xt)
{
    __shared__ float ld[64][65];
    const int t  = threadIdx.x;
    const int b0 = blockIdx.x * 64;
    const int d0 = blockIdx.y * 64;
    #pragma unroll
    for (int p = 0; p < 4; ++p) {
        int flat = p * 256 + t;
        int row = flat >> 4, c4 = flat & 15;       // row=b-local, c4*4=d-local
        float4 v = *(const float4*)&X[(size_t)(b0 + row) * Dd + d0 + c4 * 4];
        ld[row][c4*4+0] = v.x; ld[row][c4*4+1] = v.y;
        ld[row][c4*4+2] = v.z; ld[row][c4*4+3] = v.w;
    }
    __syncthreads();
    #pragma unroll
    for (int q = 0; q < 2; ++q) {
        int idx = q * 256 + t;
        int d = idx >> 3;             // 0..63 d-local
        int bs = (idx & 7) * 8;       // b-local chunk of 8
        bf16x8 o;
        #pragma unroll
        for (int j = 0; j < 8; ++j) o[j] = (short)bfr(ld[bs + j][d]);
        *(bf16x8*)&Xt[(size_t)(d0 + d) * Bsz + b0 + bs] = o;
    }
}

// ---------------------------------------------------------------------------
// BMU via MFMA with hi/lo split: score[b][n] = w2[n] - 2*dot(X[b],W[n])
// grid (16 b-tiles of 128, 16 n-tiles of 64); 4 waves: wm=b-half, wn=n-half
// wave tile 64b x 32n -> M-frags 4, N-frags 2; 32 partials per b
// ---------------------------------------------------------------------------
__global__ __launch_bounds__(256) void bmu_mfma(
    const ushort* __restrict__ Xhi, const ushort* __restrict__ Xlo,
    const ushort* __restrict__ Whi, const ushort* __restrict__ Wlo,
    const float* __restrict__ w2, float* __restrict__ pval,
    int* __restrict__ pidx)
{
    const int t = threadIdx.x, w = t >> 6, l = t & 63;
    const int wm = w & 1, wn = w >> 1;
    const int b0 = blockIdx.x * 128 + wm * 64;
    const int n0 = blockIdx.y * 64 + wn * 32;
    const int lr = l & 15, lg = l >> 4;

    f32x4 acc[4][2];
    #pragma unroll
    for (int m = 0; m < 4; ++m)
        #pragma unroll
        for (int n = 0; n < 2; ++n) { f32x4 z = {0.f,0.f,0.f,0.f}; acc[m][n] = z; }

    for (int kd = 0; kd < Dd; kd += 32) {
        bf16x8 ah[4], al[4], bh[2], bl[2];
        #pragma unroll
        for (int m = 0; m < 4; ++m) {
            size_t off = (size_t)(b0 + m*16 + lr) * Dd + kd + lg*8;
            ah[m] = *(const bf16x8*)&Xhi[off];
            al[m] = *(const bf16x8*)&Xlo[off];
        }
        #pragma unroll
        for (int n = 0; n < 2; ++n) {
            size_t off = (size_t)(n0 + n*16 + lr) * Dd + kd + lg*8;
            bh[n] = *(const bf16x8*)&Whi[off];
            bl[n] = *(const bf16x8*)&Wlo[off];
        }
        #pragma unroll
        for (int m = 0; m < 4; ++m)
            #pragma unroll
            for (int n = 0; n < 2; ++n) {
                acc[m][n] = __builtin_amdgcn_mfma_f32_16x16x32_bf16(ah[m], bh[n], acc[m][n], 0, 0, 0);
                acc[m][n] = __builtin_amdgcn_mfma_f32_16x16x32_bf16(ah[m], bl[n], acc[m][n], 0, 0, 0);
                acc[m][n] = __builtin_amdgcn_mfma_f32_16x16x32_bf16(al[m], bh[n], acc[m][n], 0, 0, 0);
            }
    }

    // epilogue: score + argmin over this block's 32 n (2 frags + 16 col lanes)
    float w2v[2]; int nidx[2];
    #pragma unroll
    for (int n = 0; n < 2; ++n) { nidx[n] = n0 + n*16 + lr; w2v[n] = w2[nidx[n]]; }

    float mv[4][4]; int mi[4][4];
    #pragma unroll
    for (int m = 0; m < 4; ++m)
        #pragma unroll
        for (int r = 0; r < 4; ++r) {
            float v0 = w2v[0] - 2.f * acc[m][0][r];
            float v1 = w2v[1] - 2.f * acc[m][1][r];
            if (v1 < v0 || (v1 == v0 && nidx[1] < nidx[0])) { mv[m][r] = v1; mi[m][r] = nidx[1]; }
            else                                            { mv[m][r] = v0; mi[m][r] = nidx[0]; }
        }
    #pragma unroll
    for (int msk = 1; msk < 16; msk <<= 1)
        #pragma unroll
        for (int m = 0; m < 4; ++m)
            #pragma unroll
            for (int r = 0; r < 4; ++r) {
                float ov = __shfl_xor(mv[m][r], msk, 64);
                int   oi = __shfl_xor(mi[m][r], msk, 64);
                if (ov < mv[m][r] || (ov == mv[m][r] && oi < mi[m][r])) { mv[m][r] = ov; mi[m][r] = oi; }
            }
    if (lr == 0) {
        #pragma unroll
        for (int m = 0; m < 4; ++m)
            #pragma unroll
            for (int r = 0; r < 4; ++r) {
                int b = b0 + m*16 + lg*4 + r;
                pval[b*32 + blockIdx.y*2 + wn] = mv[m][r];
                pidx[b*32 + blockIdx.y*2 + wn] = mi[m][r];
            }
    }
}

// ---------------------------------------------------------------------------
// final argmin over 32 partials; store BMU grid location
// ---------------------------------------------------------------------------
__global__ __launch_bounds__(256) void bmu_reduce(
    const float* __restrict__ pval, const int* __restrict__ pidx,
    const float* __restrict__ loc, float2* __restrict__ bloc)
{
    int b = blockIdx.x * 256 + threadIdx.x;
    float mv = FLT_MAX; int mi = 0x7fffffff;
    #pragma unroll
    for (int g = 0; g < 32; ++g) {
        float v = pval[b*32 + g]; int id = pidx[b*32 + g];
        if (v < mv || (v == mv && id < mi)) { mv = v; mi = id; }
    }
    bloc[b] = make_float2(loc[2*mi], loc[2*mi+1]);
}

// ---------------------------------------------------------------------------
// acc[n,d] = sum_b h[b,n]*X[b,d] via MFMA; h generated per-lane in A-frag
// layout. grid (32 n-tiles of 32, 8 b-chunks of 256); 4 waves = d-slices of 64
// ---------------------------------------------------------------------------
__global__ __launch_bounds__(256) void acc_mfma(
    const ushort* __restrict__ Xt, const float* __restrict__ loc,
    const float2* __restrict__ bloc, const int* __restrict__ step,
    const int* __restrict__ total, float* __restrict__ accw,
    float* __restrict__ hsum)
{
    const int t = threadIdx.x, w = t >> 6, l = t & 63;
    const int lr = l & 15, lg = l >> 4;
    const int n0 = blockIdx.x * 32;
    const int d0 = w * 64;
    const int bbase = blockIdx.y * 256;

    float taxa, inv2s2;
    som_params(step, total, &taxa, &inv2s2);

    float lx[2], ly[2];
    #pragma unroll
    for (int m = 0; m < 2; ++m) {
        int n = n0 + m*16 + lr;
        lx[m] = loc[2*n]; ly[m] = loc[2*n + 1];
    }

    f32x4 acc[2][4];
    #pragma unroll
    for (int m = 0; m < 2; ++m)
        #pragma unroll
        for (int nf = 0; nf < 4; ++nf) { f32x4 z = {0.f,0.f,0.f,0.f}; acc[m][nf] = z; }
    float hsacc[2] = {0.f, 0.f};

    for (int ks = 0; ks < 8; ++ks) {
        const int bk = bbase + ks*32 + lg*8;
        float2 blv[8];
        #pragma unroll
        for (int j = 0; j < 8; ++j) blv[j] = bloc[bk + j];
        bf16x8 am[2];
        #pragma unroll
        for (int m = 0; m < 2; ++m)
            #pragma unroll
            for (int j = 0; j < 8; ++j) {
                float dx = lx[m] - blv[j].x;
                float dy = ly[m] - blv[j].y;
                float e = __expf(-(dx*dx + dy*dy) * inv2s2);
                am[m][j] = (short)bfr(e);
                hsacc[m] += e;
            }
        bf16x8 bx[4];
        #pragma unroll
        for (int nf = 0; nf < 4; ++nf)
            bx[nf] = *(const bf16x8*)&Xt[(size_t)(d0 + nf*16 + lr) * Bsz + bbase + ks*32 + lg*8];
        #pragma unroll
        for (int m = 0; m < 2; ++m)
            #pragma unroll
            for (int nf = 0; nf < 4; ++nf)
                acc[m][nf] = __builtin_amdgcn_mfma_f32_16x16x32_bf16(am[m], bx[nf], acc[m][nf], 0, 0, 0);
    }

    // scatter-accumulate partial acc tile
    #pragma unroll
    for (int m = 0; m < 2; ++m)
        #pragma unroll
        for (int nf = 0; nf < 4; ++nf)
            #pragma unroll
            for (int r = 0; r < 4; ++r) {
                int n = n0 + m*16 + lg*4 + r;
                int d = d0 + nf*16 + lr;
                atomicAdd(&accw[(size_t)n * Dd + d], acc[m][nf][r]);
            }
    // hsum: only wave 0 contributes (all waves compute identical h)
    if (w == 0) {
        #pragma unroll
        for (int m = 0; m < 2; ++m) {
            float s = hsacc[m];
            s += __shfl_xor(s, 16, 64);
            s += __shfl_xor(s, 32, 64);
            if (l < 16) atomicAdd(&hsum[n0 + m*16 + l], s);
        }
    }
}

// ---------------------------------------------------------------------------
// out = W + taxa*(acc - hsum*W)/B
// ---------------------------------------------------------------------------
__global__ __launch_bounds__(256) void finish_kernel(
    const float* __restrict__ W, const float* __restrict__ acc,
    const float* __restrict__ hsum, const int* __restrict__ step,
    const int* __restrict__ total, float* __restrict__ out)
{
    float taxa, inv2s2;
    som_params(step, total, &taxa, &inv2s2);
    const float invB = 1.0f / 2048.0f;
    int i = blockIdx.x * 256 + threadIdx.x;   // float4 index, 65536 total
    int n = i >> 6;
    float hsn = hsum[n];
    float4 wv = ((const float4*)W)[i];
    float4 a  = ((const float4*)acc)[i];
    float4 o;
    o.x = wv.x + taxa * (a.x - hsn * wv.x) * invB;
    o.y = wv.y + taxa * (a.y - hsn * wv.y) * invB;
    o.z = wv.z + taxa * (a.z - hsn * wv.z) * invB;
    o.w = wv.w + taxa * (a.w - hsn * wv.w) * invB;
    ((float4*)out)[i] = o;
}

// ---------------------------------------------------------------------------
extern "C" void kernel_launch(void* const* d_in, const int* in_sizes, int n_in,
                              void* d_out, int out_size, void* d_ws, size_t ws_size,
                              hipStream_t stream)
{
    const float* X    = (const float*)d_in[0];
    const float* W    = (const float*)d_in[1];
    const float* loc  = (const float*)d_in[2];
    const int* step   = (const int*)d_in[3];
    const int* total  = (const int*)d_in[4];
    float* out = (float*)d_out;

    char* p = (char*)d_ws;
    float*  acc  = (float*)p;            p += 1048576;   // 1024*256 f32
    float*  hsum = (float*)p;            p += 4096;
    float*  w2   = (float*)p;            p += 4096;
    float*  pval = (float*)p;            p += 262144;    // 2048*32 f32
    int*    pidx = (int*)p;              p += 262144;
    float2* bloc = (float2*)p;           p += 16384;
    ushort* Xhi  = (ushort*)p;           p += 1048576;   // 2048*256 bf16
    ushort* Xlo  = (ushort*)p;           p += 1048576;
    ushort* Whi  = (ushort*)p;           p += 524288;    // 1024*256 bf16
    ushort* Wlo  = (ushort*)p;           p += 524288;
    ushort* Xt   = (ushort*)p;           p += 1048576;   // 256*2048 bf16

    hipMemsetAsync(acc, 0, 1048576 + 4096, stream);      // acc + hsum

    prep_split <<<256, 256, 0, stream>>>(W, Whi, Wlo, w2);
    prep_split <<<512, 256, 0, stream>>>(X, Xhi, Xlo, nullptr);
    prep_xt    <<<dim3(32, 4), 256, 0, stream>>>(X, Xt);
    bmu_mfma   <<<dim3(16, 16), 256, 0, stream>>>(Xhi, Xlo, Whi, Wlo, w2, pval, pidx);
    bmu_reduce <<<8, 256, 0, stream>>>(pval, pidx, loc, bloc);
    acc_mfma   <<<dim3(32, 8), 256, 0, stream>>>(Xt, loc, bloc, step, total, acc, hsum);
    finish_kernel<<<256, 256, 0, stream>>>(W, acc, hsum, step, total, out);
}